// Round 5
// baseline (387.736 us; speedup 1.0000x reference)
//
#include <hip/hip_runtime.h>
#include <cstdint>

#define BN 2
#define HN 16
#define NN 2048
#define DD 64
#define KT 64
#define NT (NN / KT)     // 32 tiles
#define LDP 72           // bf16 LDS row stride (Kb/Vt)

typedef __attribute__((ext_vector_type(8))) short short8;
typedef __attribute__((ext_vector_type(8))) unsigned short ushort8;
typedef __attribute__((ext_vector_type(4))) float float4v;
typedef __attribute__((ext_vector_type(2))) uint32_t uint2v;
typedef __attribute__((ext_vector_type(4))) uint32_t uint4v;

static __device__ __forceinline__ unsigned short f2bf(float f){
    uint32_t u = __builtin_bit_cast(uint32_t, f);
    u += 0x7FFFu + ((u >> 16) & 1u);       // round-to-nearest-even
    return (unsigned short)(u >> 16);
}

static __device__ __forceinline__ float4v mfma_bf16(short8 a, short8 b, float4v c){
    return __builtin_amdgcn_mfma_f32_16x16x32_bf16(a, b, c, 0, 0, 0);
}

// Raw barrier: drain LDS ops only; global loads/stores stay in flight.
static __device__ __forceinline__ void barrier_lds(){
    asm volatile("s_waitcnt lgkmcnt(0)" ::: "memory");
    __builtin_amdgcn_s_barrier();
    asm volatile("" ::: "memory");
}

__launch_bounds__(256, 4)
__global__ void attn_fused_kernel(const float* __restrict__ Q,
                                  const float* __restrict__ K,
                                  const float* __restrict__ V,
                                  const float* __restrict__ Bias,
                                  float* __restrict__ Out){
    __shared__ unsigned short Kb[KT][LDP];   // K tile [kv_row][d]
    __shared__ unsigned short Vt[DD][LDP];   // V tile transposed, col XOR-swizzled
    // Pe: per-wave P-fragment exchange. [wave][s][ll][12 words]; slot lg at words lg*2..+1.
    __shared__ __align__(16) uint32_t Pe[4][4][16][12];

    const int bid = blockIdx.x;
    const int b   = bid & 1;
    const int t2  = bid >> 1;
    const int rt  = t2 & 31;
    const int h   = t2 >> 5;

    const int tid = threadIdx.x;
    const int l   = tid & 63;
    const int w   = tid >> 6;         // wave id
    const int lg  = l >> 4;           // lane group 0..3
    const int ll  = l & 15;           // this lane's q-row within the wave tile (swapped layout)

    const int qw = rt * 64 + w * 16;
    const size_t bh = (size_t)(b * HN + h);
    const float* Qg = Q + (bh * NN + qw) * DD;
    const float* Kg = K + bh * NN * DD;
    const float* Vg = V + bh * NN * DD;
    // swapped-layout bias base: lane owns q-row qw+ll, kv cols sub*16+lg*4+(0..3) per tile
    const float* BgA = Bias + (size_t)h * NN * NN + (size_t)(qw + ll) * NN + lg * 4;

    const int sr = tid >> 2;          // staging row 0..63
    const int sc = (tid & 3) << 4;    // staging col 0,16,32,48

    // ---- Q fragments (B-frag now: lane holds Q[q=ll][k=lg*8+e]) ----
    short8 qf[2];
    {
        const float* qrow = Qg + (size_t)ll * DD + lg * 8;
        #pragma unroll
        for(int ks = 0; ks < 2; ++ks){
            float4v f0 = *(const float4v*)(qrow + ks * 32);
            float4v f1 = *(const float4v*)(qrow + ks * 32 + 4);
            short8 s;
            s[0]=(short)f2bf(f0[0]); s[1]=(short)f2bf(f0[1]);
            s[2]=(short)f2bf(f0[2]); s[3]=(short)f2bf(f0[3]);
            s[4]=(short)f2bf(f1[0]); s[5]=(short)f2bf(f1[1]);
            s[6]=(short)f2bf(f1[2]); s[7]=(short)f2bf(f1[3]);
            qf[ks] = s;
        }
    }

    float lsum = 0.f;

    // =============== PASS 1: row sums (swapped QK^T; bias direct to regs) ===============
    float4v kreg[4], bv[4];
    {
        const float* src = Kg + (size_t)sr * DD + sc;
        #pragma unroll
        for(int i = 0; i < 4; ++i) kreg[i] = *(const float4v*)(src + i * 4);
        #pragma unroll
        for(int sub = 0; sub < 4; ++sub)
            bv[sub] = *(const float4v*)(BgA + sub * 16);
    }

    for(int ct = 0; ct < NT; ++ct){
        barrier_lds();                         // A
        {   // stage K(t)
            unsigned short tmp[16];
            #pragma unroll
            for(int i = 0; i < 4; ++i)
                #pragma unroll
                for(int j = 0; j < 4; ++j)
                    tmp[i*4+j] = f2bf(kreg[i][j]);
            *(ushort8*)&Kb[sr][sc]     = *(ushort8*)&tmp[0];
            *(ushort8*)&Kb[sr][sc + 8] = *(ushort8*)&tmp[8];
        }
        if(ct + 1 < NT){                       // prefetch K(t+1)
            const float* src = Kg + (size_t)((ct+1)*KT + sr) * DD + sc;
            #pragma unroll
            for(int i = 0; i < 4; ++i) kreg[i] = *(const float4v*)(src + i * 4);
        }
        barrier_lds();                         // B

        float4v bvN[4];
        if(ct + 1 < NT){                       // prefetch bias(t+1)
            #pragma unroll
            for(int sub = 0; sub < 4; ++sub)
                bvN[sub] = *(const float4v*)(BgA + (ct+1)*KT + sub * 16);
        }

        // Swapped QK^T: acc[sub] = S^T, lane (lg,ll): q=ll, kv=sub*16+lg*4+r
        float4v acc[4];
        #pragma unroll
        for(int sub = 0; sub < 4; ++sub) acc[sub] = (float4v){0.f,0.f,0.f,0.f};
        __builtin_amdgcn_s_setprio(1);
        #pragma unroll
        for(int sub = 0; sub < 4; ++sub){
            short8 k0 = *(const short8*)&Kb[sub*16 + ll][lg*8];
            short8 k1 = *(const short8*)&Kb[sub*16 + ll][32 + lg*8];
            acc[sub] = mfma_bf16(k0, qf[0], acc[sub]);
            acc[sub] = mfma_bf16(k1, qf[1], acc[sub]);
        }
        __builtin_amdgcn_s_setprio(0);

        #pragma unroll
        for(int sub = 0; sub < 4; ++sub)
            #pragma unroll
            for(int r = 0; r < 4; ++r)
                lsum += __expf(acc[sub][r] * 0.125f + bv[sub][r]);

        if(ct + 1 < NT){
            #pragma unroll
            for(int sub = 0; sub < 4; ++sub) bv[sub] = bvN[sub];
        }
    }

    // one-time cross-lane reduce: q-row ll partials live at lanes ll, ll+16, ll+32, ll+48
    lsum += __shfl_xor(lsum, 16);
    lsum += __shfl_xor(lsum, 32);
    const float rl = 1.0f / lsum;

    // =============== PASS 2: attn stores + O^T = mfma(V^T, P) ===============
    float4v oacc[4];
    #pragma unroll
    for(int ds = 0; ds < 4; ++ds) oacc[ds] = (float4v){0.f,0.f,0.f,0.f};

    float* attnA = Out + (size_t)BN*HN*NN*DD
                 + (bh * NN + qw + ll) * (size_t)NN + lg * 4;

    float4v vreg[4];
    {
        const float* ks = Kg + (size_t)sr * DD + sc;
        const float* vs = Vg + (size_t)sr * DD + sc;
        #pragma unroll
        for(int i = 0; i < 4; ++i){
            kreg[i] = *(const float4v*)(ks + i * 4);
            vreg[i] = *(const float4v*)(vs + i * 4);
        }
        #pragma unroll
        for(int sub = 0; sub < 4; ++sub)
            bv[sub] = *(const float4v*)(BgA + sub * 16);
    }

    for(int ct = 0; ct < NT; ++ct){
        barrier_lds();                         // A
        {   // stage K(t) + V(t) transposed, col XOR-swizzled
            unsigned short tmp[16];
            #pragma unroll
            for(int i = 0; i < 4; ++i)
                #pragma unroll
                for(int j = 0; j < 4; ++j)
                    tmp[i*4+j] = f2bf(kreg[i][j]);
            *(ushort8*)&Kb[sr][sc]     = *(ushort8*)&tmp[0];
            *(ushort8*)&Kb[sr][sc + 8] = *(ushort8*)&tmp[8];
            #pragma unroll
            for(int i = 0; i < 4; ++i)
                #pragma unroll
                for(int j = 0; j < 4; ++j){
                    const int d = sc + i*4 + j;
                    Vt[d][sr ^ (((d >> 4) & 3) << 4)] = f2bf(vreg[i][j]);
                }
        }
        if(ct + 1 < NT){                       // prefetch K/V(t+1)
            const float* ks = Kg + (size_t)((ct+1)*KT + sr) * DD + sc;
            const float* vs = Vg + (size_t)((ct+1)*KT + sr) * DD + sc;
            #pragma unroll
            for(int i = 0; i < 4; ++i){
                kreg[i] = *(const float4v*)(ks + i * 4);
                vreg[i] = *(const float4v*)(vs + i * 4);
            }
        }
        barrier_lds();                         // B

        float4v bvN[4];
        if(ct + 1 < NT){                       // prefetch bias(t+1)
            #pragma unroll
            for(int sub = 0; sub < 4; ++sub)
                bvN[sub] = *(const float4v*)(BgA + (ct+1)*KT + sub * 16);
        }

        float4v acc[4];
        #pragma unroll
        for(int sub = 0; sub < 4; ++sub) acc[sub] = (float4v){0.f,0.f,0.f,0.f};
        __builtin_amdgcn_s_setprio(1);
        #pragma unroll
        for(int sub = 0; sub < 4; ++sub){
            short8 k0 = *(const short8*)&Kb[sub*16 + ll][lg*8];
            short8 k1 = *(const short8*)&Kb[sub*16 + ll][32 + lg*8];
            acc[sub] = mfma_bf16(k0, qf[0], acc[sub]);
            acc[sub] = mfma_bf16(k1, qf[1], acc[sub]);
        }
        __builtin_amdgcn_s_setprio(0);

        // p = exp(s)*rl, store attn directly (vectorized), pack bf16 for PV
        float4v p4[4];
        #pragma unroll
        for(int sub = 0; sub < 4; ++sub)
            #pragma unroll
            for(int r = 0; r < 4; ++r)
                p4[sub][r] = __expf(acc[sub][r] * 0.125f + bv[sub][r]) * rl;

        #pragma unroll
        for(int sub = 0; sub < 4; ++sub)
            *(float4v*)(attnA + ct*KT + sub*16) = p4[sub];

        uint32_t pk[8];
        #pragma unroll
        for(int sub = 0; sub < 4; ++sub){
            pk[2*sub]   = (uint32_t)f2bf(p4[sub][0]) | ((uint32_t)f2bf(p4[sub][1]) << 16);
            pk[2*sub+1] = (uint32_t)f2bf(p4[sub][2]) | ((uint32_t)f2bf(p4[sub][3]) << 16);
        }
        // exchange: lane's (s)-th pair lands at Pe[w][s][ll][lg*2..+1]
        #pragma unroll
        for(int s = 0; s < 4; ++s)
            *(uint2v*)&Pe[w][s][ll][lg*2] = (uint2v){pk[2*s], pk[2*s+1]};
        // read B-frags: kv = kb*32 + lg*8 + e  <=>  [s=kb*2+(lg>>1)][ll][(lg&1)*4 .. +3]
        short8 pb[2];
        #pragma unroll
        for(int kb = 0; kb < 2; ++kb){
            uint4v u = *(const uint4v*)&Pe[w][kb*2 + (lg>>1)][ll][(lg&1)*4];
            pb[kb] = __builtin_bit_cast(short8, u);
        }

        // PV: O^T[d][q] — A = V^T frag from Vt, B = P frag
        __builtin_amdgcn_s_setprio(1);
        #pragma unroll
        for(int ds = 0; ds < 4; ++ds){
            short8 v0 = *(const short8*)&Vt[ds*16 + ll][(lg*8) ^ (ds<<4)];
            short8 v1 = *(const short8*)&Vt[ds*16 + ll][(32 + lg*8) ^ (ds<<4)];
            oacc[ds] = mfma_bf16(v0, pb[0], oacc[ds]);
            oacc[ds] = mfma_bf16(v1, pb[1], oacc[ds]);
        }
        __builtin_amdgcn_s_setprio(0);

        if(ct + 1 < NT){
            #pragma unroll
            for(int sub = 0; sub < 4; ++sub) bv[sub] = bvN[sub];
        }
    }

    // O store: lane (lg,ll) holds O[q=ll][d=ds*16+lg*4+r] -> vectorized float4
    float* outG = Out + (bh * NN + qw) * (size_t)DD;
    #pragma unroll
    for(int ds = 0; ds < 4; ++ds)
        *(float4v*)(outG + (size_t)ll * DD + ds*16 + lg*4) = oacc[ds];
}

extern "C" void kernel_launch(void* const* d_in, const int* in_sizes, int n_in,
                              void* d_out, int out_size, void* d_ws, size_t ws_size,
                              hipStream_t stream) {
    const float* q    = (const float*)d_in[0];
    const float* k    = (const float*)d_in[1];
    const float* v    = (const float*)d_in[2];
    const float* bias = (const float*)d_in[3];
    float* out = (float*)d_out;

    dim3 grid(BN * HN * (NN / 64));
    dim3 block(256);
    hipLaunchKernelGGL(attn_fused_kernel, grid, block, 0, stream, q, k, v, bias, out);
}